// Round 15
// baseline (304.329 us; speedup 1.0000x reference)
//
#include <hip/hip_runtime.h>
#include <math.h>

#define B 32
#define NH 32
#define NKV 8
#define GRP 4
#define HD 128
#define DIM 4096
#define NQKV 6144   // (NH + 2*NKV) * HD
#define WIN 4096
#define KS 32       // split-K chunks for the skinny GEMMs
#define SPLIT 16    // attention sequence chunks
#define SCHUNK (WIN / SPLIT)   // 256 positions per chunk
#define WITER (SCHUNK / 4)     // 64 iterations per wave (4 waves = 4 pos-slots)

typedef float f32x4 __attribute__((ext_vector_type(4)));

__device__ __forceinline__ float fast_exp2(float x) {
#if __has_builtin(__builtin_amdgcn_exp2f)
  return __builtin_amdgcn_exp2f(x);
#else
  return exp2f(x);
#endif
}

// Streaming (non-temporal) loads: data touched exactly once per dispatch
// bypasses cache allocation on the read path (confirmed +33us on K/V, R13).
__device__ __forceinline__ f32x4 nt_load4(const float* p) {
  return __builtin_nontemporal_load((const f32x4*)p);
}
__device__ __forceinline__ float nt_load1(const float* p) {
  return __builtin_nontemporal_load(p);
}

// ---------------------------------------------------------------------------
// Skinny GEMM: part[kc][b][f] = sum_{k in kc} X[b][k]*W[k][f]
// Grid (N/256, KS), block 256. LDS-staged X, broadcast float4 reads.
// W is streamed with non-temporal loads (read exactly once per dispatch).
// ---------------------------------------------------------------------------
__global__ __launch_bounds__(256)
void gemv32_partial(const float* __restrict__ X, const float* __restrict__ W,
                    float* __restrict__ part, int K, int N) {
  const int f  = blockIdx.x * 256 + threadIdx.x;
  const int kc = blockIdx.y;
  const int kchunk = K / KS;
  const int k0 = kc * kchunk;

  __shared__ float xs[128][36];

  float acc[B];
#pragma unroll
  for (int b = 0; b < B; ++b) acc[b] = 0.f;

  for (int kb = 0; kb < kchunk; kb += 128) {
    __syncthreads();
    for (int idx = threadIdx.x; idx < B * 128; idx += 256) {
      int bb = idx >> 7;
      int kk = idx & 127;
      xs[kk][bb] = X[(size_t)bb * K + (k0 + kb + kk)];
    }
    __syncthreads();

    const float* wp = W + (size_t)(k0 + kb) * N + f;
#pragma unroll 4
    for (int kk = 0; kk < 128; ++kk) {
      float w = nt_load1(wp + (size_t)kk * N);
      const float4* xr = (const float4*)&xs[kk][0];
#pragma unroll
      for (int b4 = 0; b4 < 8; ++b4) {
        float4 xv = xr[b4];
        acc[b4 * 4 + 0] += xv.x * w;
        acc[b4 * 4 + 1] += xv.y * w;
        acc[b4 * 4 + 2] += xv.z * w;
        acc[b4 * 4 + 3] += xv.w * w;
      }
    }
  }

  float* pp = part + (size_t)kc * B * N + f;
#pragma unroll
  for (int b = 0; b < B; ++b) pp[(size_t)b * N] = acc[b];
}

// ---------------------------------------------------------------------------
// Reduce split-K partials: out[idx] = sum_kc part[kc][idx]
// ---------------------------------------------------------------------------
__global__ __launch_bounds__(256)
void reduce_partials(const float* __restrict__ part, float* __restrict__ out,
                     int total) {
  int idx = blockIdx.x * 256 + threadIdx.x;
  if (idx >= total) return;
  float s = 0.f;
#pragma unroll
  for (int kc = 0; kc < KS; ++kc) s += part[(size_t)kc * total + idx];
  out[idx] = s;
}

// ---------------------------------------------------------------------------
// Rotary: per (b, head) vector v (128), out[e] = sum_d v[d] * rot[d][e]
// q heads scaled by rsqrt(128)*log2(e) (fixed-base-2 softmax); k unscaled.
// ---------------------------------------------------------------------------
__global__ __launch_bounds__(128)
void rotary_kernel(const float* __restrict__ xqkv, const float* __restrict__ rot,
                   float* __restrict__ qrot, float* __restrict__ krot) {
  const int b = blockIdx.x;
  const int h = blockIdx.y;   // 0..39
  const int e = threadIdx.x;  // 0..127

  __shared__ float vec[HD];
  vec[e] = xqkv[(size_t)b * NQKV + h * HD + e];
  __syncthreads();

  float s = 0.f;
#pragma unroll 8
  for (int d = 0; d < HD; ++d) s += vec[d] * rot[d * HD + e];

  const float QSCALE = 0.08838834764831845f * 1.4426950408889634f;
  if (h < NH) {
    qrot[((size_t)b * NH + h) * HD + e] = s * QSCALE;
  } else {
    krot[((size_t)b * NKV + (h - NH)) * HD + e] = s;
  }
}

// ---------------------------------------------------------------------------
// Flash-decode attention partial (fixed-base softmax). R8 structure + NT
// loads + 2-DEEP software pipeline: iterations i+1 and i+2 are in flight
// while computing i (4 NT loads outstanding per wave, ~4KB). Named-register
// 3-stage rotation (no runtime indexing -> no scratch). Stale-cache loop +
// one-shot new-token correction. Grid (B*NKV, SPLIT), block 256.
// ---------------------------------------------------------------------------
__global__ __launch_bounds__(256)
void attn_partial(const float* __restrict__ cache_k, const float* __restrict__ cache_v,
                  const float* __restrict__ qrot, const float* __restrict__ krot,
                  const float* __restrict__ xqkv, const int* __restrict__ start_pos,
                  float* __restrict__ o_part, float* __restrict__ l_part) {
  const int pair = blockIdx.x;            // b * NKV + kvh
  const int b    = pair >> 3;
  const int kvh  = pair & 7;
  const int chunk = blockIdx.y;

  const int sp    = start_pos[0];
  const int cur   = sp & (WIN - 1);
  const int slice = (sp + 1 < WIN) ? (sp + 1) : WIN;

  const int tid  = threadIdx.x;
  const int wave = tid >> 6;
  const int lane = tid & 63;
  const int half = lane >> 5;
  const int l32  = lane & 31;

  // my two heads: half*2, half*2+1
  const float* qp = qrot + ((size_t)(b * NH + kvh * GRP + half * 2)) * HD + l32 * 4;
  const float4 q0 = *(const float4*)qp;
  const float4 q1 = *(const float4*)(qp + HD);

  const float* kbase = cache_k + ((size_t)(kvh * B + b)) * WIN * HD;
  const float* vbase = cache_v + ((size_t)(kvh * B + b)) * WIN * HD;

  float  l0 = 0.f, l1 = 0.f;
  float4 acc0 = {}, acc1 = {};

  const int s0 = chunk * SCHUNK;
  int rem = slice - s0 - wave;
  int n_i = rem <= 0 ? 0 : ((rem + 3) >> 2);
  if (n_i > WITER) n_i = WITER;

#define ATTN_BODY(K4, V4)                                                  \
  {                                                                        \
    float t0 = q0.x*K4.x + q0.y*K4.y + q0.z*K4.z + q0.w*K4.w;              \
    float t1 = q1.x*K4.x + q1.y*K4.y + q1.z*K4.z + q1.w*K4.w;              \
    t0 += __shfl_xor(t0, 1);  t1 += __shfl_xor(t1, 1);                     \
    t0 += __shfl_xor(t0, 2);  t1 += __shfl_xor(t1, 2);                     \
    t0 += __shfl_xor(t0, 4);  t1 += __shfl_xor(t1, 4);                     \
    t0 += __shfl_xor(t0, 8);  t1 += __shfl_xor(t1, 8);                     \
    t0 += __shfl_xor(t0, 16); t1 += __shfl_xor(t1, 16);                    \
    float w0 = fast_exp2(t0), w1 = fast_exp2(t1);                          \
    l0 += w0; l1 += w1;                                                    \
    acc0.x += w0*V4.x; acc0.y += w0*V4.y; acc0.z += w0*V4.z; acc0.w += w0*V4.w; \
    acc1.x += w1*V4.x; acc1.y += w1*V4.y; acc1.z += w1*V4.z; acc1.w += w1*V4.w; \
  }

  if (n_i > 0) {
    const size_t STRIDE = 4 * 128;        // 4 rows of 128 floats
    size_t off = ((size_t)(s0 + wave) * 32 + l32) * 4;
    f32x4 kA = nt_load4(kbase + off);
    f32x4 vA = nt_load4(vbase + off);
    if (n_i == 1) {
      ATTN_BODY(kA, vA);
    } else {
      off += STRIDE;
      f32x4 kB = nt_load4(kbase + off);
      f32x4 vB = nt_load4(vbase + off);
#pragma unroll 2
      for (int i = 2; i < n_i; ++i) {
        off += STRIDE;
        f32x4 kC = nt_load4(kbase + off);
        f32x4 vC = nt_load4(vbase + off);
        ATTN_BODY(kA, vA);
        kA = kB; vA = vB; kB = kC; vB = vC;
      }
      ATTN_BODY(kA, vA);
      ATTN_BODY(kB, vB);
    }
  }

  // Correct the new-token position: subtract stale contribution, add new one.
  // Owning wave: p = s0 + i*4 + wave == cur  ->  chunk and wave match.
  if (chunk == (cur >> 8) && wave == (cur & 3)) {
    const float4 kst = *(const float4*)(kbase + (size_t)cur * HD + l32 * 4);
    const float4 vst = *(const float4*)(vbase + (size_t)cur * HD + l32 * 4);
    const float4 knew = *(const float4*)(krot + ((size_t)(b * NKV + kvh)) * HD + l32 * 4);
    const float4 vnew = *(const float4*)(xqkv + (size_t)b * NQKV + (NH + NKV + kvh) * HD + l32 * 4);

    float s0st = q0.x*kst.x + q0.y*kst.y + q0.z*kst.z + q0.w*kst.w;
    float s1st = q1.x*kst.x + q1.y*kst.y + q1.z*kst.z + q1.w*kst.w;
    float s0nw = q0.x*knew.x + q0.y*knew.y + q0.z*knew.z + q0.w*knew.w;
    float s1nw = q1.x*knew.x + q1.y*knew.y + q1.z*knew.z + q1.w*knew.w;
#pragma unroll
    for (int off2 = 1; off2 <= 16; off2 <<= 1) {
      s0st += __shfl_xor(s0st, off2);
      s1st += __shfl_xor(s1st, off2);
      s0nw += __shfl_xor(s0nw, off2);
      s1nw += __shfl_xor(s1nw, off2);
    }
    float w0st = fast_exp2(s0st), w1st = fast_exp2(s1st);
    float w0nw = fast_exp2(s0nw), w1nw = fast_exp2(s1nw);
    l0 += w0nw - w0st;
    l1 += w1nw - w1st;
    acc0.x += w0nw*vnew.x - w0st*vst.x;  acc0.y += w0nw*vnew.y - w0st*vst.y;
    acc0.z += w0nw*vnew.z - w0st*vst.z;  acc0.w += w0nw*vnew.w - w0st*vst.w;
    acc1.x += w1nw*vnew.x - w1st*vst.x;  acc1.y += w1nw*vnew.y - w1st*vst.y;
    acc1.z += w1nw*vnew.z - w1st*vst.z;  acc1.w += w1nw*vnew.w - w1st*vst.w;
  }

  // combine the 4 waves via LDS (halves hold different heads -> no xor-32)
  __shared__ float red_l[4][GRP];
  __shared__ float red_o[4][GRP][HD];
  {
    const int h0 = half * 2;
    *(float4*)&red_o[wave][h0 + 0][l32 * 4] = acc0;
    *(float4*)&red_o[wave][h0 + 1][l32 * 4] = acc1;
    if (l32 == 0) {
      red_l[wave][h0 + 0] = l0;
      red_l[wave][h0 + 1] = l1;
    }
  }
  __syncthreads();

  const size_t pc = (size_t)pair * SPLIT + chunk;
  for (int idx = tid; idx < GRP * HD; idx += 256) {
    int g = idx >> 7, d = idx & 127;
    float o = red_o[0][g][d] + red_o[1][g][d] + red_o[2][g][d] + red_o[3][g][d];
    o_part[(pc * GRP + g) * HD + d] = o;
  }
  if (tid < GRP) {
    l_part[pc * GRP + tid] =
        red_l[0][tid] + red_l[1][tid] + red_l[2][tid] + red_l[3][tid];
  }
}

// ---------------------------------------------------------------------------
// Combine the SPLIT chunk partials -> attn_out[b][n*128 + d]
// ---------------------------------------------------------------------------
__global__ __launch_bounds__(128)
void attn_combine(const float* __restrict__ o_part, const float* __restrict__ l_part,
                  float* __restrict__ attn_out) {
  const int bid = blockIdx.x;   // b*32 + n
  const int b = bid >> 5, n = bid & 31;
  const int pair = b * NKV + (n >> 2);
  const int g = n & 3;
  const int d = threadIdx.x;

  float lsum = 0.f, osum = 0.f;
#pragma unroll
  for (int c = 0; c < SPLIT; ++c) {
    size_t pc = (size_t)pair * SPLIT + c;
    lsum += l_part[pc * GRP + g];
    osum += o_part[(pc * GRP + g) * HD + d];
  }
  attn_out[(size_t)b * DIM + n * HD + d] = osum / lsum;
}

// ---------------------------------------------------------------------------
extern "C" void kernel_launch(void* const* d_in, const int* in_sizes, int n_in,
                              void* d_out, int out_size, void* d_ws, size_t ws_size,
                              hipStream_t stream) {
  (void)in_sizes; (void)n_in; (void)out_size; (void)ws_size;

  const float* x    = (const float*)d_in[0];  // [1,1,32,4096]
  const float* wqkv = (const float*)d_in[1];  // [4096,6144]
  const float* wo   = (const float*)d_in[2];  // [4096,4096]
  const float* rot  = (const float*)d_in[3];  // [128,128]
  const float* ck   = (const float*)d_in[4];  // [8,32,4096,128]
  const float* cv   = (const float*)d_in[5];  // [8,32,4096,128]
  const int*   sp   = (const int*)d_in[6];    // scalar
  float* out = (float*)d_out;                 // [32,4096]

  float* ws       = (float*)d_ws;
  float* part     = ws;
  float* o_part   = ws;   // aliases part (lifetimes disjoint)
  float* xqkv     = part + (size_t)KS * B * NQKV;
  float* qrot     = xqkv + (size_t)B * NQKV;
  float* krot     = qrot + (size_t)B * NH * HD;
  float* l_part   = krot + (size_t)B * NKV * HD;
  float* attn_out = l_part + (size_t)B * NKV * SPLIT * GRP;

  // 1) xqkv = x @ wqkv  (split-K partials, then reduce)
  gemv32_partial<<<dim3(NQKV / 256, KS), 256, 0, stream>>>(x, wqkv, part, DIM, NQKV);
  reduce_partials<<<(B * NQKV) / 256, 256, 0, stream>>>(part, xqkv, B * NQKV);

  // 2) rotary on q (scaled; exp2 base folded in) and k
  rotary_kernel<<<dim3(B, NH + NKV), 128, 0, stream>>>(xqkv, rot, qrot, krot);

  // 3) flash-decode attention (NT loads + 2-deep pipeline)
  attn_partial<<<dim3(B * NKV, SPLIT), 256, 0, stream>>>(ck, cv, qrot, krot, xqkv,
                                                         sp, o_part, l_part);
  attn_combine<<<B * NH, 128, 0, stream>>>(o_part, l_part, attn_out);

  // 4) dense = attn_out @ wo (weights streamed non-temporally)
  gemv32_partial<<<dim3(DIM / 256, KS), 256, 0, stream>>>(attn_out, wo, part, DIM, DIM);
  reduce_partials<<<(B * DIM) / 256, 256, 0, stream>>>(part, out, B * DIM);
}

// Round 16
// 272.884 us; speedup vs baseline: 1.1152x; 1.1152x over previous
//
#include <hip/hip_runtime.h>
#include <math.h>

#define B 32
#define NH 32
#define NKV 8
#define GRP 4
#define HD 128
#define DIM 4096
#define NQKV 6144   // (NH + 2*NKV) * HD
#define WIN 4096
#define KS 32       // split-K chunks for the skinny GEMMs
#define SPLIT 16    // attention sequence chunks
#define SCHUNK (WIN / SPLIT)   // 256 positions per chunk
#define WSPAN (SCHUNK / 4)     // 64 contiguous positions per wave

typedef float f32x4 __attribute__((ext_vector_type(4)));

__device__ __forceinline__ float fast_exp2(float x) {
#if __has_builtin(__builtin_amdgcn_exp2f)
  return __builtin_amdgcn_exp2f(x);
#else
  return exp2f(x);
#endif
}

// Streaming (non-temporal) loads: data touched exactly once per dispatch
// bypasses cache allocation on the read path (confirmed +33us on K/V, R13).
__device__ __forceinline__ f32x4 nt_load4(const float* p) {
  return __builtin_nontemporal_load((const f32x4*)p);
}
__device__ __forceinline__ float nt_load1(const float* p) {
  return __builtin_nontemporal_load(p);
}

// ---------------------------------------------------------------------------
// Skinny GEMM: part[kc][b][f] = sum_{k in kc} X[b][k]*W[k][f]
// Grid (N/256, KS), block 256. LDS-staged X, broadcast float4 reads.
// W is streamed with non-temporal loads (read exactly once per dispatch).
// ---------------------------------------------------------------------------
__global__ __launch_bounds__(256)
void gemv32_partial(const float* __restrict__ X, const float* __restrict__ W,
                    float* __restrict__ part, int K, int N) {
  const int f  = blockIdx.x * 256 + threadIdx.x;
  const int kc = blockIdx.y;
  const int kchunk = K / KS;
  const int k0 = kc * kchunk;

  __shared__ float xs[128][36];

  float acc[B];
#pragma unroll
  for (int b = 0; b < B; ++b) acc[b] = 0.f;

  for (int kb = 0; kb < kchunk; kb += 128) {
    __syncthreads();
    for (int idx = threadIdx.x; idx < B * 128; idx += 256) {
      int bb = idx >> 7;
      int kk = idx & 127;
      xs[kk][bb] = X[(size_t)bb * K + (k0 + kb + kk)];
    }
    __syncthreads();

    const float* wp = W + (size_t)(k0 + kb) * N + f;
#pragma unroll 4
    for (int kk = 0; kk < 128; ++kk) {
      float w = nt_load1(wp + (size_t)kk * N);
      const float4* xr = (const float4*)&xs[kk][0];
#pragma unroll
      for (int b4 = 0; b4 < 8; ++b4) {
        float4 xv = xr[b4];
        acc[b4 * 4 + 0] += xv.x * w;
        acc[b4 * 4 + 1] += xv.y * w;
        acc[b4 * 4 + 2] += xv.z * w;
        acc[b4 * 4 + 3] += xv.w * w;
      }
    }
  }

  float* pp = part + (size_t)kc * B * N + f;
#pragma unroll
  for (int b = 0; b < B; ++b) pp[(size_t)b * N] = acc[b];
}

// ---------------------------------------------------------------------------
// Reduce split-K partials: out[idx] = sum_kc part[kc][idx]
// ---------------------------------------------------------------------------
__global__ __launch_bounds__(256)
void reduce_partials(const float* __restrict__ part, float* __restrict__ out,
                     int total) {
  int idx = blockIdx.x * 256 + threadIdx.x;
  if (idx >= total) return;
  float s = 0.f;
#pragma unroll
  for (int kc = 0; kc < KS; ++kc) s += part[(size_t)kc * total + idx];
  out[idx] = s;
}

// ---------------------------------------------------------------------------
// Rotary: per (b, head) vector v (128), out[e] = sum_d v[d] * rot[d][e]
// q heads scaled by rsqrt(128)*log2(e) (fixed-base-2 softmax); k unscaled.
// ---------------------------------------------------------------------------
__global__ __launch_bounds__(128)
void rotary_kernel(const float* __restrict__ xqkv, const float* __restrict__ rot,
                   float* __restrict__ qrot, float* __restrict__ krot) {
  const int b = blockIdx.x;
  const int h = blockIdx.y;   // 0..39
  const int e = threadIdx.x;  // 0..127

  __shared__ float vec[HD];
  vec[e] = xqkv[(size_t)b * NQKV + h * HD + e];
  __syncthreads();

  float s = 0.f;
#pragma unroll 8
  for (int d = 0; d < HD; ++d) s += vec[d] * rot[d * HD + e];

  const float QSCALE = 0.08838834764831845f * 1.4426950408889634f;
  if (h < NH) {
    qrot[((size_t)b * NH + h) * HD + e] = s * QSCALE;
  } else {
    krot[((size_t)b * NKV + (h - NH)) * HD + e] = s;
  }
}

// ---------------------------------------------------------------------------
// Flash-decode attention partial (fixed-base softmax). R14 structure (NT
// loads, 1-deep prefetch, half 0 -> heads 0-1 / half 1 -> heads 2-3) with
// SEQUENTIAL PER-WAVE STREAMS: wave w owns the contiguous 64-row span
// [s0 + w*64, s0 + (w+1)*64) so each wave's NT read stream is purely
// sequential (32KB K + 32KB V), instead of hopping 2KB every iteration.
// Stale-cache loop + one-shot new-token correction.
// Grid (B*NKV, SPLIT), block 256.
// ---------------------------------------------------------------------------
__global__ __launch_bounds__(256)
void attn_partial(const float* __restrict__ cache_k, const float* __restrict__ cache_v,
                  const float* __restrict__ qrot, const float* __restrict__ krot,
                  const float* __restrict__ xqkv, const int* __restrict__ start_pos,
                  float* __restrict__ o_part, float* __restrict__ l_part) {
  const int pair = blockIdx.x;            // b * NKV + kvh
  const int b    = pair >> 3;
  const int kvh  = pair & 7;
  const int chunk = blockIdx.y;

  const int sp    = start_pos[0];
  const int cur   = sp & (WIN - 1);
  const int slice = (sp + 1 < WIN) ? (sp + 1) : WIN;

  const int tid  = threadIdx.x;
  const int wave = tid >> 6;
  const int lane = tid & 63;
  const int half = lane >> 5;
  const int l32  = lane & 31;

  // my two heads: half*2, half*2+1
  const float* qp = qrot + ((size_t)(b * NH + kvh * GRP + half * 2)) * HD + l32 * 4;
  const float4 q0 = *(const float4*)qp;
  const float4 q1 = *(const float4*)(qp + HD);

  const float* kbase = cache_k + ((size_t)(kvh * B + b)) * WIN * HD;
  const float* vbase = cache_v + ((size_t)(kvh * B + b)) * WIN * HD;

  float  l0 = 0.f, l1 = 0.f;
  float4 acc0 = {}, acc1 = {};

  const int s0 = chunk * SCHUNK;
  const int w0 = s0 + wave * WSPAN;       // my wave's first position
  int n_i = slice - w0;
  if (n_i < 0) n_i = 0;
  if (n_i > WSPAN) n_i = WSPAN;

#define ATTN_BODY(K4, V4)                                                  \
  {                                                                        \
    float t0 = q0.x*K4.x + q0.y*K4.y + q0.z*K4.z + q0.w*K4.w;              \
    float t1 = q1.x*K4.x + q1.y*K4.y + q1.z*K4.z + q1.w*K4.w;              \
    t0 += __shfl_xor(t0, 1);  t1 += __shfl_xor(t1, 1);                     \
    t0 += __shfl_xor(t0, 2);  t1 += __shfl_xor(t1, 2);                     \
    t0 += __shfl_xor(t0, 4);  t1 += __shfl_xor(t1, 4);                     \
    t0 += __shfl_xor(t0, 8);  t1 += __shfl_xor(t1, 8);                     \
    t0 += __shfl_xor(t0, 16); t1 += __shfl_xor(t1, 16);                    \
    float w0_ = fast_exp2(t0), w1_ = fast_exp2(t1);                        \
    l0 += w0_; l1 += w1_;                                                  \
    acc0.x += w0_*V4.x; acc0.y += w0_*V4.y; acc0.z += w0_*V4.z; acc0.w += w0_*V4.w; \
    acc1.x += w1_*V4.x; acc1.y += w1_*V4.y; acc1.z += w1_*V4.z; acc1.w += w1_*V4.w; \
  }

  if (n_i > 0) {
    size_t off = ((size_t)w0 * 32 + l32) * 4;   // float offset; +128/row
    f32x4 k4 = nt_load4(kbase + off);
    f32x4 v4 = nt_load4(vbase + off);
#pragma unroll 2
    for (int i = 1; i < n_i; ++i) {
      off += 128;
      f32x4 kn = nt_load4(kbase + off);
      f32x4 vn = nt_load4(vbase + off);
      ATTN_BODY(k4, v4);
      k4 = kn; v4 = vn;
    }
    ATTN_BODY(k4, v4);
  }

  // Correct the new-token position: subtract stale contribution, add new one.
  // p = w0 + i == cur  ->  chunk == cur>>8 and wave == (cur>>6)&3.
  if (chunk == (cur >> 8) && wave == ((cur >> 6) & 3)) {
    const float4 kst = *(const float4*)(kbase + (size_t)cur * HD + l32 * 4);
    const float4 vst = *(const float4*)(vbase + (size_t)cur * HD + l32 * 4);
    const float4 knew = *(const float4*)(krot + ((size_t)(b * NKV + kvh)) * HD + l32 * 4);
    const float4 vnew = *(const float4*)(xqkv + (size_t)b * NQKV + (NH + NKV + kvh) * HD + l32 * 4);

    float s0st = q0.x*kst.x + q0.y*kst.y + q0.z*kst.z + q0.w*kst.w;
    float s1st = q1.x*kst.x + q1.y*kst.y + q1.z*kst.z + q1.w*kst.w;
    float s0nw = q0.x*knew.x + q0.y*knew.y + q0.z*knew.z + q0.w*knew.w;
    float s1nw = q1.x*knew.x + q1.y*knew.y + q1.z*knew.z + q1.w*knew.w;
#pragma unroll
    for (int off2 = 1; off2 <= 16; off2 <<= 1) {
      s0st += __shfl_xor(s0st, off2);
      s1st += __shfl_xor(s1st, off2);
      s0nw += __shfl_xor(s0nw, off2);
      s1nw += __shfl_xor(s1nw, off2);
    }
    float w0st = fast_exp2(s0st), w1st = fast_exp2(s1st);
    float w0nw = fast_exp2(s0nw), w1nw = fast_exp2(s1nw);
    l0 += w0nw - w0st;
    l1 += w1nw - w1st;
    acc0.x += w0nw*vnew.x - w0st*vst.x;  acc0.y += w0nw*vnew.y - w0st*vst.y;
    acc0.z += w0nw*vnew.z - w0st*vst.z;  acc0.w += w0nw*vnew.w - w0st*vst.w;
    acc1.x += w1nw*vnew.x - w1st*vst.x;  acc1.y += w1nw*vnew.y - w1st*vst.y;
    acc1.z += w1nw*vnew.z - w1st*vst.z;  acc1.w += w1nw*vnew.w - w1st*vst.w;
  }

  // combine the 4 waves via LDS (halves hold different heads -> no xor-32)
  __shared__ float red_l[4][GRP];
  __shared__ float red_o[4][GRP][HD];
  {
    const int h0 = half * 2;
    *(float4*)&red_o[wave][h0 + 0][l32 * 4] = acc0;
    *(float4*)&red_o[wave][h0 + 1][l32 * 4] = acc1;
    if (l32 == 0) {
      red_l[wave][h0 + 0] = l0;
      red_l[wave][h0 + 1] = l1;
    }
  }
  __syncthreads();

  const size_t pc = (size_t)pair * SPLIT + chunk;
  for (int idx = tid; idx < GRP * HD; idx += 256) {
    int g = idx >> 7, d = idx & 127;
    float o = red_o[0][g][d] + red_o[1][g][d] + red_o[2][g][d] + red_o[3][g][d];
    o_part[(pc * GRP + g) * HD + d] = o;
  }
  if (tid < GRP) {
    l_part[pc * GRP + tid] =
        red_l[0][tid] + red_l[1][tid] + red_l[2][tid] + red_l[3][tid];
  }
}

// ---------------------------------------------------------------------------
// Combine the SPLIT chunk partials -> attn_out[b][n*128 + d]
// ---------------------------------------------------------------------------
__global__ __launch_bounds__(128)
void attn_combine(const float* __restrict__ o_part, const float* __restrict__ l_part,
                  float* __restrict__ attn_out) {
  const int bid = blockIdx.x;   // b*32 + n
  const int b = bid >> 5, n = bid & 31;
  const int pair = b * NKV + (n >> 2);
  const int g = n & 3;
  const int d = threadIdx.x;

  float lsum = 0.f, osum = 0.f;
#pragma unroll
  for (int c = 0; c < SPLIT; ++c) {
    size_t pc = (size_t)pair * SPLIT + c;
    lsum += l_part[pc * GRP + g];
    osum += o_part[(pc * GRP + g) * HD + d];
  }
  attn_out[(size_t)b * DIM + n * HD + d] = osum / lsum;
}

// ---------------------------------------------------------------------------
extern "C" void kernel_launch(void* const* d_in, const int* in_sizes, int n_in,
                              void* d_out, int out_size, void* d_ws, size_t ws_size,
                              hipStream_t stream) {
  (void)in_sizes; (void)n_in; (void)out_size; (void)ws_size;

  const float* x    = (const float*)d_in[0];  // [1,1,32,4096]
  const float* wqkv = (const float*)d_in[1];  // [4096,6144]
  const float* wo   = (const float*)d_in[2];  // [4096,4096]
  const float* rot  = (const float*)d_in[3];  // [128,128]
  const float* ck   = (const float*)d_in[4];  // [8,32,4096,128]
  const float* cv   = (const float*)d_in[5];  // [8,32,4096,128]
  const int*   sp   = (const int*)d_in[6];    // scalar
  float* out = (float*)d_out;                 // [32,4096]

  float* ws       = (float*)d_ws;
  float* part     = ws;
  float* o_part   = ws;   // aliases part (lifetimes disjoint)
  float* xqkv     = part + (size_t)KS * B * NQKV;
  float* qrot     = xqkv + (size_t)B * NQKV;
  float* krot     = qrot + (size_t)B * NH * HD;
  float* l_part   = krot + (size_t)B * NKV * HD;
  float* attn_out = l_part + (size_t)B * NKV * SPLIT * GRP;

  // 1) xqkv = x @ wqkv  (split-K partials, then reduce)
  gemv32_partial<<<dim3(NQKV / 256, KS), 256, 0, stream>>>(x, wqkv, part, DIM, NQKV);
  reduce_partials<<<(B * NQKV) / 256, 256, 0, stream>>>(part, xqkv, B * NQKV);

  // 2) rotary on q (scaled; exp2 base folded in) and k
  rotary_kernel<<<dim3(B, NH + NKV), 128, 0, stream>>>(xqkv, rot, qrot, krot);

  // 3) flash-decode attention (NT loads, sequential 32KB per-wave streams)
  attn_partial<<<dim3(B * NKV, SPLIT), 256, 0, stream>>>(ck, cv, qrot, krot, xqkv,
                                                         sp, o_part, l_part);
  attn_combine<<<B * NH, 128, 0, stream>>>(o_part, l_part, attn_out);

  // 4) dense = attn_out @ wo (weights streamed non-temporally)
  gemv32_partial<<<dim3(DIM / 256, KS), 256, 0, stream>>>(attn_out, wo, part, DIM, DIM);
  reduce_partials<<<(B * DIM) / 256, 256, 0, stream>>>(part, out, B * DIM);
}